// Round 1
// baseline (13886.888 us; speedup 1.0000x reference)
//
#include <hip/hip_runtime.h>
#include <stdint.h>

// Problem dims
#define T_   512
#define B_   64
#define E_   512
#define H_   1024
#define G4   4096      // 4*H
#define TCH  128       // T chunk for gates buffer
#define MCH  (TCH*B_)  // 8192 rows per chunk
#define REC_NWG 64

typedef __attribute__((ext_vector_type(8))) short short8;
typedef __attribute__((ext_vector_type(4))) float f32x4;

__device__ __forceinline__ unsigned short f2bf(float f) {
  unsigned u = __builtin_bit_cast(unsigned, f);
  u += 0x7FFFu + ((u >> 16) & 1u);
  return (unsigned short)(u >> 16);
}
__device__ __forceinline__ float bf2f(unsigned short h) {
  return __builtin_bit_cast(float, ((unsigned)h) << 16);
}
__device__ __forceinline__ float sigm(float x) { return 1.f / (1.f + __expf(-x)); }
__device__ __forceinline__ float tanh_f(float x) {
  x = fmaxf(x, -30.f);                 // avoid inf/inf NaN for very negative x
  float e = __expf(-2.f * x);
  return (1.f - e) / (1.f + e);
}

// Gate-permuted column index n in [0,4096): n = (kblk, gate, uu) -> orig = gate*1024 + kblk*16 + uu
__device__ __forceinline__ int perm_orig(int n) {
  return ((n >> 4) & 3) * 1024 + (n >> 6) * 16 + (n & 15);
}

// ---------------- prep: weight convert+permute (rows of [4096][K]) ----------------
__global__ void prep_w_kernel(const float* __restrict__ src, unsigned short* __restrict__ dst,
                              int kshift) {   // K/4 = 1<<kshift
  const int idx = blockIdx.x * 256 + threadIdx.x;
  const int n = idx >> kshift;
  const int k4 = idx & ((1 << kshift) - 1);
  const int K = 4 << kshift;
  const int orig = perm_orig(n);
  const float4 v = *((const float4*)(src + (size_t)orig * K) + k4);
  uint2 pk;
  pk.x = (unsigned)f2bf(v.x) | ((unsigned)f2bf(v.y) << 16);
  pk.y = (unsigned)f2bf(v.z) | ((unsigned)f2bf(v.w) << 16);
  *((uint2*)(dst + (size_t)n * K) + k4) = pk;
}

__global__ void prep_bias_kernel(const float* __restrict__ bih0, const float* __restrict__ bhh0,
                                 const float* __restrict__ bih1, const float* __restrict__ bhh1,
                                 float* __restrict__ b0, float* __restrict__ b1) {
  const int n = blockIdx.x * 256 + threadIdx.x;  // 4096
  const int o = perm_orig(n);
  b0[n] = bih0[o] + bhh0[o];
  b1[n] = bih1[o] + bhh1[o];
}

// ---------------- embedding gather -> bf16 [32768][512] ----------------
__global__ void embed_kernel(const int* __restrict__ tok, const float* __restrict__ emb,
                             unsigned short* __restrict__ xe) {
  const int idx = blockIdx.x * 256 + threadIdx.x;  // 16384 blocks
  const int row = idx >> 7, c4 = idx & 127;
  const int t = tok[row];
  const float4 v = *((const float4*)(emb + (size_t)t * E_) + c4);
  uint2 pk;
  pk.x = (unsigned)f2bf(v.x) | ((unsigned)f2bf(v.y) << 16);
  pk.y = (unsigned)f2bf(v.z) | ((unsigned)f2bf(v.w) << 16);
  *((uint2*)(xe + (size_t)row * E_) + c4) = pk;
}

// ---------------- projection GEMM: C[m][n] = sum_k A[m][k]*Bw[n][k] + bias[n] ----------------
// A: [8192][K] bf16, Bw: [4096][K] bf16 (gate-permuted rows), C: [8192][4096] bf16
__global__ __launch_bounds__(256, 2) void proj_kernel(
    const unsigned short* __restrict__ A, const unsigned short* __restrict__ Bw,
    const float* __restrict__ bias, unsigned short* __restrict__ Cout, int K) {
  __shared__ unsigned short lsA[128 * 32];
  __shared__ unsigned short lsB[128 * 32];
  const int tid = threadIdx.x;
  const int row0 = blockIdx.x * 128;
  const int col0 = blockIdx.y * 128;
  const int w = tid >> 6, l = tid & 63, l16 = l & 15, kq = l >> 4;
  const int wr = w >> 1, wc = w & 1;
  const int sr = tid >> 2, sc = (tid & 3) * 8;
  f32x4 acc[4][4];
#pragma unroll
  for (int m = 0; m < 4; ++m)
#pragma unroll
    for (int n = 0; n < 4; ++n) acc[m][n] = (f32x4){0.f, 0.f, 0.f, 0.f};

  const unsigned short* Ab  = A  + (size_t)(row0 + sr) * K + sc;
  const unsigned short* Ab2 = Ab + (size_t)64 * K;
  const unsigned short* Bb  = Bw + (size_t)(col0 + sr) * K + sc;
  const unsigned short* Bb2 = Bb + (size_t)64 * K;

  for (int k0 = 0; k0 < K; k0 += 32) {
    short8 va0 = *(const short8*)(Ab + k0);
    short8 va1 = *(const short8*)(Ab2 + k0);
    short8 vb0 = *(const short8*)(Bb + k0);
    short8 vb1 = *(const short8*)(Bb2 + k0);
    __syncthreads();  // previous iter's reads done
    *(short8*)&lsA[sr * 32 + sc] = va0;
    *(short8*)&lsA[(64 + sr) * 32 + sc] = va1;
    *(short8*)&lsB[sr * 32 + sc] = vb0;
    *(short8*)&lsB[(64 + sr) * 32 + sc] = vb1;
    __syncthreads();
    short8 af[4], bfr[4];
#pragma unroll
    for (int m = 0; m < 4; ++m) af[m] = *(const short8*)&lsA[(wr * 64 + m * 16 + l16) * 32 + kq * 8];
#pragma unroll
    for (int n = 0; n < 4; ++n) bfr[n] = *(const short8*)&lsB[(wc * 64 + n * 16 + l16) * 32 + kq * 8];
#pragma unroll
    for (int m = 0; m < 4; ++m)
#pragma unroll
      for (int n = 0; n < 4; ++n)
        acc[m][n] = __builtin_amdgcn_mfma_f32_16x16x32_bf16(af[m], bfr[n], acc[m][n], 0, 0, 0);
  }
  // epilogue: D row=(lane>>4)*4+reg, col=lane&15 within each 16x16 frag
#pragma unroll
  for (int n = 0; n < 4; ++n) {
    const int col = col0 + wc * 64 + n * 16 + l16;
    const float bv = bias[col];
#pragma unroll
    for (int m = 0; m < 4; ++m)
#pragma unroll
      for (int r = 0; r < 4; ++r) {
        const int row = row0 + wr * 64 + m * 16 + kq * 4 + r;
        Cout[(size_t)row * G4 + col] = f2bf(acc[m][n][r] + bv);
      }
  }
}

// ---------------- persistent recurrent kernel ----------------
// 64 WGs x 256 thr; WG kblk owns hidden units [kblk*16, kblk*16+16) = perm cols [kblk*64, +64).
// Waves: cs = col strip (2 gates), kh2 = K half (split-K). Whh frags live in VGPRs.
__global__ __launch_bounds__(256, 1) void rec_kernel(
    const unsigned short* __restrict__ Whh,  // [4096][1024] bf16 permuted rows
    const unsigned short* __restrict__ xw,   // [TCH*64][4096] bf16 chunk (xW + biases)
    unsigned short* __restrict__ hbuf,       // [512][64][1024] bf16
    float* __restrict__ cbuf,                // [64][1024] f32
    int t0, unsigned gen_base, unsigned* __restrict__ bar) {
  // 92,160 B static LDS: first 4*64*17 floats used as gate exchange buffer; rest pads so
  // only 1 WG/CU fits (keeps the 64 WGs spread over 64 CUs).
  __shared__ float smem[23040];
  const int tid = threadIdx.x;
  const int kblk = blockIdx.x;
  const int w = tid >> 6;
  const int l = tid & 63;
  const int l16 = l & 15;
  const int kq = l >> 4;
  const int cs = w & 1;
  const int kh2 = w >> 1;

  // load B fragments (16 cols x 512 K per wave-pair arrangement): 32 x short8 = 128 VGPR
  short8 bfrag[2][16];
#pragma unroll
  for (int n = 0; n < 2; ++n) {
    const unsigned short* bp = Whh + (size_t)(kblk * 64 + cs * 32 + n * 16 + l16) * H_ + kh2 * 512 + kq * 8;
#pragma unroll
    for (int ks = 0; ks < 16; ++ks) bfrag[n][ks] = *(const short8*)(bp + ks * 32);
  }

  const int u0 = (tid & 7) * 2;   // unit pair
  const int r0 = (tid >> 3) * 2;  // row pair
  float c00, c01, c10, c11;
  if (t0 == 0) {
    c00 = c01 = c10 = c11 = 0.f;
  } else {
    const float* cb = cbuf + (size_t)r0 * H_ + kblk * 16 + u0;
    c00 = cb[0]; c01 = cb[1]; c10 = cb[H_]; c11 = cb[H_ + 1];
  }

  for (int s = 0; s < TCH; ++s) {
    const int t = t0 + s;
    f32x4 acc[4][2];
#pragma unroll
    for (int rf = 0; rf < 4; ++rf)
#pragma unroll
      for (int n = 0; n < 2; ++n) acc[rf][n] = (f32x4){0.f, 0.f, 0.f, 0.f};

    if (t > 0) {
      const unsigned short* hp = hbuf + (size_t)(t - 1) * (B_ * H_) + (size_t)l16 * H_ + kh2 * 512 + kq * 8;
#pragma unroll
      for (int ks = 0; ks < 16; ++ks) {
        short8 a0 = *(const short8*)(hp + 0 * 16 * H_ + ks * 32);
        short8 a1 = *(const short8*)(hp + 1 * 16 * H_ + ks * 32);
        short8 a2 = *(const short8*)(hp + 2 * 16 * H_ + ks * 32);
        short8 a3 = *(const short8*)(hp + 3 * 16 * H_ + ks * 32);
#pragma unroll
        for (int n = 0; n < 2; ++n) {
          acc[0][n] = __builtin_amdgcn_mfma_f32_16x16x32_bf16(a0, bfrag[n][ks], acc[0][n], 0, 0, 0);
          acc[1][n] = __builtin_amdgcn_mfma_f32_16x16x32_bf16(a1, bfrag[n][ks], acc[1][n], 0, 0, 0);
          acc[2][n] = __builtin_amdgcn_mfma_f32_16x16x32_bf16(a2, bfrag[n][ks], acc[2][n], 0, 0, 0);
          acc[3][n] = __builtin_amdgcn_mfma_f32_16x16x32_bf16(a3, bfrag[n][ks], acc[3][n], 0, 0, 0);
        }
      }
    }

    // split-K partial sums into LDS (gate g = cs*2+n)
    if (kh2 == 0) {
#pragma unroll
      for (int rf = 0; rf < 4; ++rf)
#pragma unroll
        for (int n = 0; n < 2; ++n)
#pragma unroll
          for (int r = 0; r < 4; ++r)
            smem[((cs * 2 + n) * 64 + (rf * 16 + kq * 4 + r)) * 17 + l16] = acc[rf][n][r];
    }
    __syncthreads();
    if (kh2 == 1) {
#pragma unroll
      for (int rf = 0; rf < 4; ++rf)
#pragma unroll
        for (int n = 0; n < 2; ++n)
#pragma unroll
          for (int r = 0; r < 4; ++r)
            smem[((cs * 2 + n) * 64 + (rf * 16 + kq * 4 + r)) * 17 + l16] += acc[rf][n][r];
    }
    __syncthreads();

    // elementwise LSTM update: thread owns 2 rows x 2 units
    const unsigned short* xwt = xw + (size_t)s * (B_ * G4);
    float hv[2][2];
#pragma unroll
    for (int dr = 0; dr < 2; ++dr)
#pragma unroll
      for (int du = 0; du < 2; ++du) {
        const int row = r0 + dr, u = u0 + du;
        const size_t xb = (size_t)row * G4 + kblk * 64;
        float gi = smem[(0 * 64 + row) * 17 + u] + bf2f(xwt[xb + 0 * 16 + u]);
        float gf = smem[(1 * 64 + row) * 17 + u] + bf2f(xwt[xb + 1 * 16 + u]);
        float gg = smem[(2 * 64 + row) * 17 + u] + bf2f(xwt[xb + 2 * 16 + u]);
        float go = smem[(3 * 64 + row) * 17 + u] + bf2f(xwt[xb + 3 * 16 + u]);
        float iv = sigm(gi), fv = sigm(gf), gv = tanh_f(gg), ov = sigm(go);
        float& c = dr ? (du ? c11 : c10) : (du ? c01 : c00);
        c = fv * c + iv * gv;
        hv[dr][du] = ov * tanh_f(c);
      }
    // publish h (agent-scope write-through so all XCDs see it after the barrier)
#pragma unroll
    for (int dr = 0; dr < 2; ++dr) {
      unsigned pk = (unsigned)f2bf(hv[dr][0]) | ((unsigned)f2bf(hv[dr][1]) << 16);
      unsigned* dst = (unsigned*)(hbuf + (size_t)t * (B_ * H_) + (size_t)(r0 + dr) * H_ + kblk * 16 + u0);
      __hip_atomic_store(dst, pk, __ATOMIC_RELAXED, __HIP_MEMORY_SCOPE_AGENT);
    }

    // grid barrier (sense via monotonically increasing generation)
    if (s < TCH - 1) {
      __syncthreads();
      if (tid == 0) {
        const unsigned target = gen_base + (unsigned)s + 1u;
        unsigned old = __hip_atomic_fetch_add(&bar[0], 1u, __ATOMIC_ACQ_REL, __HIP_MEMORY_SCOPE_AGENT);
        if (old == REC_NWG - 1) {
          __hip_atomic_store(&bar[0], 0u, __ATOMIC_RELAXED, __HIP_MEMORY_SCOPE_AGENT);
          __hip_atomic_store(&bar[1], target, __ATOMIC_RELEASE, __HIP_MEMORY_SCOPE_AGENT);
        } else {
          while (__hip_atomic_load(&bar[1], __ATOMIC_ACQUIRE, __HIP_MEMORY_SCOPE_AGENT) < target)
            __builtin_amdgcn_s_sleep(2);
        }
      }
      __syncthreads();
    }
  }
  // save c for next chunk
  float* cb = cbuf + (size_t)r0 * H_ + kblk * 16 + u0;
  cb[0] = c00; cb[1] = c01; cb[H_] = c10; cb[H_ + 1] = c11;
}

// ---------------- head: out[b] = 10*sigmoid(h2_last[b,:] . Wd + bd) ----------------
__global__ void head_kernel(const unsigned short* __restrict__ hl, const float* __restrict__ Wd,
                            const float* __restrict__ bdp, float* __restrict__ out) {
  __shared__ float p[256];
  const int tid = threadIdx.x, b = tid >> 2, q = tid & 3;
  const unsigned short* hr = hl + (size_t)b * H_ + q * 256;
  const float* wd = Wd + q * 256;
  float s = 0.f;
#pragma unroll 4
  for (int j = 0; j < 256; j += 8) {
    short8 v = *(const short8*)(hr + j);
#pragma unroll
    for (int i = 0; i < 8; ++i) s += bf2f((unsigned short)v[i]) * wd[j + i];
  }
  p[tid] = s;
  __syncthreads();
  if (q == 0) {
    float tot = p[tid] + p[tid + 1] + p[tid + 2] + p[tid + 3] + bdp[0];
    out[b] = 10.f * sigm(tot);
  }
}

// ---------------- host ----------------
extern "C" void kernel_launch(void* const* d_in, const int* in_sizes, int n_in,
                              void* d_out, int out_size, void* d_ws, size_t ws_size,
                              hipStream_t stream) {
  const int*   tokens = (const int*)d_in[0];
  const float* emb  = (const float*)d_in[1];
  const float* Wih0 = (const float*)d_in[2];
  const float* Whh0 = (const float*)d_in[3];
  const float* bih0 = (const float*)d_in[4];
  const float* bhh0 = (const float*)d_in[5];
  const float* Wih1 = (const float*)d_in[6];
  const float* Whh1 = (const float*)d_in[7];
  const float* bih1 = (const float*)d_in[8];
  const float* bhh1 = (const float*)d_in[9];
  const float* Wd   = (const float*)d_in[10];
  const float* bd   = (const float*)d_in[11];
  float* out = (float*)d_out;
  char* ws = (char*)d_ws;

  // ws layout (bytes)
  const size_t O_WIH0 = 0;                       // 4096*512*2  = 4 MiB
  const size_t O_WHH0 = O_WIH0 + 4194304;        // 8 MiB
  const size_t O_WIH1 = O_WHH0 + 8388608;        // 8 MiB
  const size_t O_WHH1 = O_WIH1 + 8388608;        // 8 MiB
  const size_t O_B0   = O_WHH1 + 8388608;        // 16 KiB
  const size_t O_B1   = O_B0 + 16384;            // 16 KiB
  const size_t O_XEMB = O_B1 + 16384;            // 32 MiB
  const size_t O_GATE = O_XEMB + 33554432;       // 64 MiB (one T-chunk)
  const size_t O_H1   = O_GATE + 67108864;       // 64 MiB
  const size_t O_H2   = O_H1 + 67108864;         // 64 MiB
  const size_t O_CB   = O_H2 + 67108864;         // 256 KiB
  const size_t O_BAR  = O_CB + 262144;           // 256 B

  unsigned short* wih0p = (unsigned short*)(ws + O_WIH0);
  unsigned short* whh0p = (unsigned short*)(ws + O_WHH0);
  unsigned short* wih1p = (unsigned short*)(ws + O_WIH1);
  unsigned short* whh1p = (unsigned short*)(ws + O_WHH1);
  float* bias0 = (float*)(ws + O_B0);
  float* bias1 = (float*)(ws + O_B1);
  unsigned short* xemb  = (unsigned short*)(ws + O_XEMB);
  unsigned short* gates = (unsigned short*)(ws + O_GATE);
  unsigned short* h1    = (unsigned short*)(ws + O_H1);
  unsigned short* h2    = (unsigned short*)(ws + O_H2);
  float* cbuf = (float*)(ws + O_CB);
  unsigned* bar = (unsigned*)(ws + O_BAR);

  hipMemsetAsync(ws + O_BAR, 0, 256, stream);

  prep_w_kernel<<<2048, 256, 0, stream>>>(Wih0, wih0p, 7);   // K=512
  prep_w_kernel<<<4096, 256, 0, stream>>>(Whh0, whh0p, 8);   // K=1024
  prep_w_kernel<<<4096, 256, 0, stream>>>(Wih1, wih1p, 8);
  prep_w_kernel<<<4096, 256, 0, stream>>>(Whh1, whh1p, 8);
  prep_bias_kernel<<<16, 256, 0, stream>>>(bih0, bhh0, bih1, bhh1, bias0, bias1);
  embed_kernel<<<16384, 256, 0, stream>>>(tokens, emb, xemb);

  for (int c = 0; c < 4; ++c) {
    proj_kernel<<<dim3(64, 32), 256, 0, stream>>>(xemb + (size_t)c * MCH * E_, wih0p, bias0, gates, E_);
    rec_kernel<<<REC_NWG, 256, 0, stream>>>(whh0p, gates, h1, cbuf, c * TCH, (unsigned)(c * TCH), bar);
  }
  for (int c = 0; c < 4; ++c) {
    proj_kernel<<<dim3(64, 32), 256, 0, stream>>>(h1 + (size_t)c * MCH * H_, wih1p, bias1, gates, H_);
    rec_kernel<<<REC_NWG, 256, 0, stream>>>(whh1p, gates, h2, cbuf, c * TCH, (unsigned)(512 + c * TCH), bar);
  }
  head_kernel<<<1, 256, 0, stream>>>(h2 + (size_t)511 * B_ * H_, Wd, bd, out);

  (void)in_sizes; (void)n_in; (void)out_size; (void)ws_size;
}

// Round 2
// 10667.898 us; speedup vs baseline: 1.3017x; 1.3017x over previous
//
#include <hip/hip_runtime.h>
#include <stdint.h>

// Problem dims
#define T_   512
#define B_   64
#define E_   512
#define H_   1024
#define G4   4096      // 4*H
#define TCH  128       // T chunk for gates buffer
#define MCH  (TCH*B_)  // 8192 rows per chunk
#define BH   (B_*H_)

typedef __attribute__((ext_vector_type(8))) short short8;
typedef __attribute__((ext_vector_type(4))) float f32x4;

__device__ __forceinline__ unsigned short f2bf(float f) {
  unsigned u = __builtin_bit_cast(unsigned, f);
  u += 0x7FFFu + ((u >> 16) & 1u);
  return (unsigned short)(u >> 16);
}
__device__ __forceinline__ float bf2f(unsigned short h) {
  return __builtin_bit_cast(float, ((unsigned)h) << 16);
}
__device__ __forceinline__ float sigm(float x) { return 1.f / (1.f + __expf(-x)); }
__device__ __forceinline__ float tanh_f(float x) {
  x = fmaxf(x, -30.f);
  float e = __expf(-2.f * x);
  return (1.f - e) / (1.f + e);
}

// perm1: n = (kblk, gate, uu16) -> orig = gate*1024 + kblk*16 + uu   (L1 / proj layout)
__device__ __forceinline__ int perm1_orig(int n) {
  return ((n >> 4) & 3) * 1024 + (n >> 6) * 16 + (n & 15);
}
// perm2: n = (kblk2, gate, uu8) -> orig = gate*1024 + kblk2*8 + uu   (L2 layout)
__device__ __forceinline__ int perm2_orig(int n) {
  return ((n >> 3) & 3) * 1024 + (n >> 5) * 8 + (n & 7);
}

// ---------------- prep: weight convert+permute ----------------
__global__ void prep_w_kernel(const float* __restrict__ src, unsigned short* __restrict__ dst,
                              int kshift) {   // K/4 = 1<<kshift; dst pitch = K, perm1
  const int idx = blockIdx.x * 256 + threadIdx.x;
  const int n = idx >> kshift;
  const int k4 = idx & ((1 << kshift) - 1);
  const int K = 4 << kshift;
  const int orig = perm1_orig(n);
  const float4 v = *((const float4*)(src + (size_t)orig * K) + k4);
  uint2 pk;
  pk.x = (unsigned)f2bf(v.x) | ((unsigned)f2bf(v.y) << 16);
  pk.y = (unsigned)f2bf(v.z) | ((unsigned)f2bf(v.w) << 16);
  *((uint2*)(dst + (size_t)n * K) + k4) = pk;
}

// fused L2 weight: dst[4096][2048], rows perm2; koff=0 <- Wih1 (K=1024), koff=1024 <- Whh1
__global__ void prep_w2_kernel(const float* __restrict__ src, unsigned short* __restrict__ dst,
                               int koff) {
  const int idx = blockIdx.x * 256 + threadIdx.x;  // 4096 blocks
  const int n = idx >> 8;           // row
  const int k4 = idx & 255;         // K/4 = 256
  const int orig = perm2_orig(n);
  const float4 v = *((const float4*)(src + (size_t)orig * 1024) + k4);
  uint2 pk;
  pk.x = (unsigned)f2bf(v.x) | ((unsigned)f2bf(v.y) << 16);
  pk.y = (unsigned)f2bf(v.z) | ((unsigned)f2bf(v.w) << 16);
  *((uint2*)(dst + (size_t)n * 2048 + koff) + k4) = pk;
}

__global__ void prep_bias_kernel(const float* __restrict__ bih0, const float* __restrict__ bhh0,
                                 const float* __restrict__ bih1, const float* __restrict__ bhh1,
                                 float* __restrict__ b0, float* __restrict__ b2) {
  const int n = blockIdx.x * 256 + threadIdx.x;  // 4096
  const int o1 = perm1_orig(n);
  const int o2 = perm2_orig(n);
  b0[n] = bih0[o1] + bhh0[o1];
  b2[n] = bih1[o2] + bhh1[o2];
}

// ---------------- embedding gather -> bf16 [32768][512] ----------------
__global__ void embed_kernel(const int* __restrict__ tok, const float* __restrict__ emb,
                             unsigned short* __restrict__ xe) {
  const int idx = blockIdx.x * 256 + threadIdx.x;
  const int row = idx >> 7, c4 = idx & 127;
  const int t = tok[row];
  const float4 v = *((const float4*)(emb + (size_t)t * E_) + c4);
  uint2 pk;
  pk.x = (unsigned)f2bf(v.x) | ((unsigned)f2bf(v.y) << 16);
  pk.y = (unsigned)f2bf(v.z) | ((unsigned)f2bf(v.w) << 16);
  *((uint2*)(xe + (size_t)row * E_) + c4) = pk;
}

// ---------------- projection GEMM (layer-1 input proj only) ----------------
__global__ __launch_bounds__(256, 2) void proj_kernel(
    const unsigned short* __restrict__ A, const unsigned short* __restrict__ Bw,
    const float* __restrict__ bias, unsigned short* __restrict__ Cout, int K) {
  __shared__ unsigned short lsA[128 * 32];
  __shared__ unsigned short lsB[128 * 32];
  const int tid = threadIdx.x;
  const int row0 = blockIdx.x * 128;
  const int col0 = blockIdx.y * 128;
  const int w = tid >> 6, l = tid & 63, l16 = l & 15, kq = l >> 4;
  const int wr = w >> 1, wc = w & 1;
  const int sr = tid >> 2, sc = (tid & 3) * 8;
  f32x4 acc[4][4];
#pragma unroll
  for (int m = 0; m < 4; ++m)
#pragma unroll
    for (int n = 0; n < 4; ++n) acc[m][n] = (f32x4){0.f, 0.f, 0.f, 0.f};

  const unsigned short* Ab  = A  + (size_t)(row0 + sr) * K + sc;
  const unsigned short* Ab2 = Ab + (size_t)64 * K;
  const unsigned short* Bb  = Bw + (size_t)(col0 + sr) * K + sc;
  const unsigned short* Bb2 = Bb + (size_t)64 * K;

  for (int k0 = 0; k0 < K; k0 += 32) {
    short8 va0 = *(const short8*)(Ab + k0);
    short8 va1 = *(const short8*)(Ab2 + k0);
    short8 vb0 = *(const short8*)(Bb + k0);
    short8 vb1 = *(const short8*)(Bb2 + k0);
    __syncthreads();
    *(short8*)&lsA[sr * 32 + sc] = va0;
    *(short8*)&lsA[(64 + sr) * 32 + sc] = va1;
    *(short8*)&lsB[sr * 32 + sc] = vb0;
    *(short8*)&lsB[(64 + sr) * 32 + sc] = vb1;
    __syncthreads();
    short8 af[4], bfr[4];
#pragma unroll
    for (int m = 0; m < 4; ++m) af[m] = *(const short8*)&lsA[(wr * 64 + m * 16 + l16) * 32 + kq * 8];
#pragma unroll
    for (int n = 0; n < 4; ++n) bfr[n] = *(const short8*)&lsB[(wc * 64 + n * 16 + l16) * 32 + kq * 8];
#pragma unroll
    for (int m = 0; m < 4; ++m)
#pragma unroll
      for (int n = 0; n < 4; ++n)
        acc[m][n] = __builtin_amdgcn_mfma_f32_16x16x32_bf16(af[m], bfr[n], acc[m][n], 0, 0, 0);
  }
#pragma unroll
  for (int n = 0; n < 4; ++n) {
    const int col = col0 + wc * 64 + n * 16 + l16;
    const float bv = bias[col];
#pragma unroll
    for (int m = 0; m < 4; ++m)
#pragma unroll
      for (int r = 0; r < 4; ++r) {
        const int row = row0 + wr * 64 + m * 16 + kq * 4 + r;
        Cout[(size_t)row * G4 + col] = f2bf(acc[m][n][r] + bv);
      }
  }
}

// ---------------- distributed-flag grid barrier ----------------
__device__ __forceinline__ void grid_bar(unsigned* __restrict__ flags, int bid, int tid,
                                         int w, int l, unsigned target) {
  __syncthreads();  // drains each wave's h-publish stores (vmcnt 0) before arrival
  if (tid == 0)
    __hip_atomic_store(&flags[bid], target, __ATOMIC_RELEASE, __HIP_MEMORY_SCOPE_AGENT);
  if (w == 0) {
    for (;;) {
      unsigned v0 = __hip_atomic_load(&flags[l],       __ATOMIC_RELAXED, __HIP_MEMORY_SCOPE_AGENT);
      unsigned v1 = __hip_atomic_load(&flags[l + 64],  __ATOMIC_RELAXED, __HIP_MEMORY_SCOPE_AGENT);
      unsigned v2 = __hip_atomic_load(&flags[l + 128], __ATOMIC_RELAXED, __HIP_MEMORY_SCOPE_AGENT);
      unsigned mn = v0 < v1 ? v0 : v1;
      if (v2 < mn) mn = v2;
      if (__all((int)(mn >= target))) break;
      __builtin_amdgcn_s_sleep(1);
    }
  }
  __syncthreads();
  __builtin_amdgcn_fence(__ATOMIC_ACQUIRE, "agent");  // one invalidate after the wait
}

// ---------------- fused persistent recurrent kernel (both layers pipelined) ----------------
// grid = 192: bid<64 -> L1 (kblk=bid, 64 perm1 cols, K=1024 from h1[t-1]);
//             bid>=64 -> L2 (j=bid-64, 32 perm2 cols, K=2048 from [h1[t2]; h2[t2-1]]).
// Macro-step m = t0+s: L1 computes h1[m], L2 computes h2[m-1]. One grid barrier per step.
__global__ __launch_bounds__(256, 1) void fused_kernel(
    const unsigned short* __restrict__ Whh0p,   // [4096][1024] perm1
    const unsigned short* __restrict__ W2p,     // [4096][2048] perm2
    const unsigned short* __restrict__ xw,      // [S*64][4096] layer-1 gates chunk
    const float* __restrict__ bias2,            // [4096] perm2
    unsigned short* __restrict__ h1buf, unsigned short* __restrict__ h2buf,
    float* __restrict__ c1buf, float* __restrict__ c2buf,
    int t0, int S, unsigned* __restrict__ flags) {
  // 86016 B: forces 1 WG/CU (2x86016 > 160 KiB). Exchange uses stride-18 pads.
  __shared__ float smem[21504];
  const int tid = threadIdx.x, bid = blockIdx.x;
  const int w = tid >> 6, l = tid & 63, l16 = l & 15, kq = l >> 4;

  if (bid < 64) {
    // ================= layer 1 =================
    const int kblk = bid;
    short8 bf[4][8];   // [gate-strip][ks] 128 VGPR, resident across all steps
#pragma unroll
    for (int st = 0; st < 4; ++st) {
      const unsigned short* bp = Whh0p + (size_t)(kblk * 64 + st * 16 + l16) * H_ + w * 256 + kq * 8;
#pragma unroll
      for (int ks = 0; ks < 8; ++ks) bf[st][ks] = *(const short8*)(bp + ks * 32);
    }
    const int u0 = (tid & 7) * 2, r0 = (tid >> 3) * 2;
    float c00, c01, c10, c11;
    if (t0 == 0) {
      c00 = c01 = c10 = c11 = 0.f;
    } else {
      const float* cb = c1buf + (size_t)r0 * H_ + kblk * 16 + u0;
      c00 = cb[0]; c01 = cb[1]; c10 = cb[H_]; c11 = cb[H_ + 1];
    }
    unsigned xwa[8], xwn[8];
#pragma unroll
    for (int q = 0; q < 8; ++q) xwn[q] = 0;
    if (t0 < T_) {
      const unsigned short* xb = xw + (size_t)r0 * G4 + kblk * 64 + u0;
#pragma unroll
      for (int dr = 0; dr < 2; ++dr)
#pragma unroll
        for (int g = 0; g < 4; ++g) xwa[dr * 4 + g] = *(const unsigned*)(xb + dr * G4 + g * 16);
    }
    for (int s = 0; s < S; ++s) {
      const int t1 = t0 + s;
      if (t1 < T_) {
        f32x4 acc[4][4];
#pragma unroll
        for (int rf = 0; rf < 4; ++rf)
#pragma unroll
          for (int st = 0; st < 4; ++st) acc[rf][st] = (f32x4){0.f, 0.f, 0.f, 0.f};
        if (t1 > 0) {
          const unsigned short* hp = h1buf + (size_t)(t1 - 1) * BH + (size_t)l16 * H_ + w * 256 + kq * 8;
#pragma unroll
          for (int ks = 0; ks < 8; ++ks) {
            short8 a0 = *(const short8*)(hp + ks * 32);
            short8 a1 = *(const short8*)(hp + 16 * H_ + ks * 32);
            short8 a2 = *(const short8*)(hp + 32 * H_ + ks * 32);
            short8 a3 = *(const short8*)(hp + 48 * H_ + ks * 32);
#pragma unroll
            for (int st = 0; st < 4; ++st) {
              acc[0][st] = __builtin_amdgcn_mfma_f32_16x16x32_bf16(a0, bf[st][ks], acc[0][st], 0, 0, 0);
              acc[1][st] = __builtin_amdgcn_mfma_f32_16x16x32_bf16(a1, bf[st][ks], acc[1][st], 0, 0, 0);
              acc[2][st] = __builtin_amdgcn_mfma_f32_16x16x32_bf16(a2, bf[st][ks], acc[2][st], 0, 0, 0);
              acc[3][st] = __builtin_amdgcn_mfma_f32_16x16x32_bf16(a3, bf[st][ks], acc[3][st], 0, 0, 0);
            }
          }
        }
        // split-K partials: kh = w
#pragma unroll
        for (int rf = 0; rf < 4; ++rf)
#pragma unroll
          for (int st = 0; st < 4; ++st)
#pragma unroll
            for (int r = 0; r < 4; ++r)
              smem[(size_t)((w * 4 + st) * 64 + rf * 16 + kq * 4 + r) * 18 + l16] = acc[rf][st][r];
        __syncthreads();
        float hv[2][2];
#pragma unroll
        for (int dr = 0; dr < 2; ++dr)
#pragma unroll
          for (int du = 0; du < 2; ++du) {
            const int row = r0 + dr, u = u0 + du;
            float gs[4];
#pragma unroll
            for (int g = 0; g < 4; ++g) {
              gs[g] = smem[(size_t)((0 + g) * 64 + row) * 18 + u]
                    + smem[(size_t)((4 + g) * 64 + row) * 18 + u]
                    + smem[(size_t)((8 + g) * 64 + row) * 18 + u]
                    + smem[(size_t)((12 + g) * 64 + row) * 18 + u]
                    + bf2f((unsigned short)(xwa[dr * 4 + g] >> (du * 16)));
            }
            float iv = sigm(gs[0]), fv = sigm(gs[1]), gv = tanh_f(gs[2]), ov = sigm(gs[3]);
            float& c = dr ? (du ? c11 : c10) : (du ? c01 : c00);
            c = fv * c + iv * gv;
            hv[dr][du] = ov * tanh_f(c);
          }
#pragma unroll
        for (int dr = 0; dr < 2; ++dr) {
          unsigned pk = (unsigned)f2bf(hv[dr][0]) | ((unsigned)f2bf(hv[dr][1]) << 16);
          unsigned* dst = (unsigned*)(h1buf + (size_t)t1 * BH + (size_t)(r0 + dr) * H_ + kblk * 16 + u0);
          __hip_atomic_store(dst, pk, __ATOMIC_RELAXED, __HIP_MEMORY_SCOPE_AGENT);
        }
        // prefetch next step's xw so it flies during the barrier wait
        if (s + 1 < S) {
          const unsigned short* xb = xw + (size_t)(s + 1) * (B_ * G4) + (size_t)r0 * G4 + kblk * 64 + u0;
#pragma unroll
          for (int dr = 0; dr < 2; ++dr)
#pragma unroll
            for (int g = 0; g < 4; ++g) xwn[dr * 4 + g] = *(const unsigned*)(xb + dr * G4 + g * 16);
        }
      }
      if (s < S - 1) {
        grid_bar(flags, bid, tid, w, l, (unsigned)(t0 + s + 1));
#pragma unroll
        for (int q = 0; q < 8; ++q) xwa[q] = xwn[q];
      }
    }
    if (t0 < T_) {
      float* cb = c1buf + (size_t)r0 * H_ + kblk * 16 + u0;
      cb[0] = c00; cb[1] = c01; cb[H_] = c10; cb[H_ + 1] = c11;
    }
  } else {
    // ================= layer 2 (fused input+recurrent GEMM, K=2048) =================
    const int j = bid - 64;
    short8 bf[2][16];  // [strip][ks] 128 VGPR
#pragma unroll
    for (int st = 0; st < 2; ++st) {
      const unsigned short* bp = W2p + (size_t)(j * 32 + st * 16 + l16) * 2048 + w * 512 + kq * 8;
#pragma unroll
      for (int ks = 0; ks < 16; ++ks) bf[st][ks] = *(const short8*)(bp + ks * 32);
    }
    const int u0 = (tid & 3) * 2, r0 = (tid >> 2) * 2;  // valid for tid<128
    float c2r[2][2];
    float bias_r[2][4];
    if (tid < 128) {
#pragma unroll
      for (int du = 0; du < 2; ++du)
#pragma unroll
        for (int g = 0; g < 4; ++g) bias_r[du][g] = bias2[j * 32 + g * 8 + u0 + du];
      if (t0 >= 2) {
#pragma unroll
        for (int dr = 0; dr < 2; ++dr)
#pragma unroll
          for (int du = 0; du < 2; ++du)
            c2r[dr][du] = c2buf[(size_t)(r0 + dr) * H_ + j * 8 + u0 + du];
      } else {
#pragma unroll
        for (int dr = 0; dr < 2; ++dr)
#pragma unroll
          for (int du = 0; du < 2; ++du) c2r[dr][du] = 0.f;
      }
    }
    for (int s = 0; s < S; ++s) {
      const int t2 = t0 + s - 1;
      if (t2 >= 0 && t2 < T_) {
        f32x4 acc[4][2];
#pragma unroll
        for (int rf = 0; rf < 4; ++rf)
#pragma unroll
          for (int st = 0; st < 2; ++st) acc[rf][st] = (f32x4){0.f, 0.f, 0.f, 0.f};
        const bool half2 = (w >= 2);         // waves 2,3: Whh1 half (A = h2[t2-1])
        if (!half2 || t2 > 0) {
          const unsigned short* ap = half2
              ? (h2buf + (size_t)(t2 - 1) * BH + (size_t)l16 * H_ + (w - 2) * 512 + kq * 8)
              : (h1buf + (size_t)t2 * BH + (size_t)l16 * H_ + w * 512 + kq * 8);
#pragma unroll
          for (int ks = 0; ks < 16; ++ks) {
            short8 a0 = *(const short8*)(ap + ks * 32);
            short8 a1 = *(const short8*)(ap + 16 * H_ + ks * 32);
            short8 a2 = *(const short8*)(ap + 32 * H_ + ks * 32);
            short8 a3 = *(const short8*)(ap + 48 * H_ + ks * 32);
#pragma unroll
            for (int st = 0; st < 2; ++st) {
              acc[0][st] = __builtin_amdgcn_mfma_f32_16x16x32_bf16(a0, bf[st][ks], acc[0][st], 0, 0, 0);
              acc[1][st] = __builtin_amdgcn_mfma_f32_16x16x32_bf16(a1, bf[st][ks], acc[1][st], 0, 0, 0);
              acc[2][st] = __builtin_amdgcn_mfma_f32_16x16x32_bf16(a2, bf[st][ks], acc[2][st], 0, 0, 0);
              acc[3][st] = __builtin_amdgcn_mfma_f32_16x16x32_bf16(a3, bf[st][ks], acc[3][st], 0, 0, 0);
            }
          }
        }
#pragma unroll
        for (int rf = 0; rf < 4; ++rf)
#pragma unroll
          for (int st = 0; st < 2; ++st)
#pragma unroll
            for (int r = 0; r < 4; ++r)
              smem[(size_t)((w * 2 + st) * 64 + rf * 16 + kq * 4 + r) * 18 + l16] = acc[rf][st][r];
        __syncthreads();
        if (tid < 128) {
          float hv[2][2];
#pragma unroll
          for (int dr = 0; dr < 2; ++dr)
#pragma unroll
            for (int du = 0; du < 2; ++du) {
              const int row = r0 + dr, u = u0 + du;
              float gs[4];
#pragma unroll
              for (int g = 0; g < 4; ++g) {
                const int n = g * 8 + u;                    // local col in [0,32)
                const int strip = n >> 4, pos = n & 15;
                gs[g] = smem[(size_t)((0 * 2 + strip) * 64 + row) * 18 + pos]
                      + smem[(size_t)((1 * 2 + strip) * 64 + row) * 18 + pos]
                      + smem[(size_t)((2 * 2 + strip) * 64 + row) * 18 + pos]
                      + smem[(size_t)((3 * 2 + strip) * 64 + row) * 18 + pos]
                      + bias_r[du][g];
              }
              float iv = sigm(gs[0]), fv = sigm(gs[1]), gv = tanh_f(gs[2]), ov = sigm(gs[3]);
              c2r[dr][du] = fv * c2r[dr][du] + iv * gv;
              hv[dr][du] = ov * tanh_f(c2r[dr][du]);
            }
#pragma unroll
          for (int dr = 0; dr < 2; ++dr) {
            unsigned pk = (unsigned)f2bf(hv[dr][0]) | ((unsigned)f2bf(hv[dr][1]) << 16);
            unsigned* dst = (unsigned*)(h2buf + (size_t)t2 * BH + (size_t)(r0 + dr) * H_ + j * 8 + u0);
            __hip_atomic_store(dst, pk, __ATOMIC_RELAXED, __HIP_MEMORY_SCOPE_AGENT);
          }
        }
      }
      if (s < S - 1) grid_bar(flags, bid, tid, w, l, (unsigned)(t0 + s + 1));
    }
    if (tid < 128) {
#pragma unroll
      for (int dr = 0; dr < 2; ++dr)
#pragma unroll
        for (int du = 0; du < 2; ++du)
          c2buf[(size_t)(r0 + dr) * H_ + j * 8 + u0 + du] = c2r[dr][du];
    }
  }
}

// ---------------- head ----------------
__global__ void head_kernel(const unsigned short* __restrict__ hl, const float* __restrict__ Wd,
                            const float* __restrict__ bdp, float* __restrict__ out) {
  __shared__ float p[256];
  const int tid = threadIdx.x, b = tid >> 2, q = tid & 3;
  const unsigned short* hr = hl + (size_t)b * H_ + q * 256;
  const float* wd = Wd + q * 256;
  float s = 0.f;
#pragma unroll 4
  for (int j = 0; j < 256; j += 8) {
    short8 v = *(const short8*)(hr + j);
#pragma unroll
    for (int i = 0; i < 8; ++i) s += bf2f((unsigned short)v[i]) * wd[j + i];
  }
  p[tid] = s;
  __syncthreads();
  if (q == 0) {
    float tot = p[tid] + p[tid + 1] + p[tid + 2] + p[tid + 3] + bdp[0];
    out[b] = 10.f * sigm(tot);
  }
}

// ---------------- host ----------------
extern "C" void kernel_launch(void* const* d_in, const int* in_sizes, int n_in,
                              void* d_out, int out_size, void* d_ws, size_t ws_size,
                              hipStream_t stream) {
  const int*   tokens = (const int*)d_in[0];
  const float* emb  = (const float*)d_in[1];
  const float* Wih0 = (const float*)d_in[2];
  const float* Whh0 = (const float*)d_in[3];
  const float* bih0 = (const float*)d_in[4];
  const float* bhh0 = (const float*)d_in[5];
  const float* Wih1 = (const float*)d_in[6];
  const float* Whh1 = (const float*)d_in[7];
  const float* bih1 = (const float*)d_in[8];
  const float* bhh1 = (const float*)d_in[9];
  const float* Wd   = (const float*)d_in[10];
  const float* bd   = (const float*)d_in[11];
  float* out = (float*)d_out;
  char* ws = (char*)d_ws;

  // ws layout (bytes), total ~252.6 MiB
  const size_t O_WIH0 = 0;                       // 4 MiB
  const size_t O_WHH0 = O_WIH0 + 4194304;        // 8 MiB
  const size_t O_W2   = O_WHH0 + 8388608;        // 16 MiB
  const size_t O_B0   = O_W2   + 16777216;       // 16 KiB
  const size_t O_B2   = O_B0   + 16384;          // 16 KiB
  const size_t O_XEMB = O_B2   + 16384;          // 32 MiB
  const size_t O_GATE = O_XEMB + 33554432;       // 64 MiB
  const size_t O_H1   = O_GATE + 67108864;       // 64 MiB
  const size_t O_H2   = O_H1   + 67108864;       // 64 MiB
  const size_t O_C1   = O_H2   + 67108864;       // 256 KiB
  const size_t O_C2   = O_C1   + 262144;         // 256 KiB
  const size_t O_FLG  = O_C2   + 262144;         // 4 KiB

  unsigned short* wih0p = (unsigned short*)(ws + O_WIH0);
  unsigned short* whh0p = (unsigned short*)(ws + O_WHH0);
  unsigned short* w2p   = (unsigned short*)(ws + O_W2);
  float* bias0 = (float*)(ws + O_B0);
  float* bias2 = (float*)(ws + O_B2);
  unsigned short* xemb  = (unsigned short*)(ws + O_XEMB);
  unsigned short* gates = (unsigned short*)(ws + O_GATE);
  unsigned short* h1    = (unsigned short*)(ws + O_H1);
  unsigned short* h2    = (unsigned short*)(ws + O_H2);
  float* c1buf = (float*)(ws + O_C1);
  float* c2buf = (float*)(ws + O_C2);
  unsigned* flags = (unsigned*)(ws + O_FLG);

  hipMemsetAsync(ws + O_FLG, 0, 4096, stream);

  prep_w_kernel<<<2048, 256, 0, stream>>>(Wih0, wih0p, 7);    // K=512, perm1
  prep_w_kernel<<<4096, 256, 0, stream>>>(Whh0, whh0p, 8);    // K=1024, perm1
  prep_w2_kernel<<<4096, 256, 0, stream>>>(Wih1, w2p, 0);     // perm2, K-offset 0
  prep_w2_kernel<<<4096, 256, 0, stream>>>(Whh1, w2p, 1024);  // perm2, K-offset 1024
  prep_bias_kernel<<<16, 256, 0, stream>>>(bih0, bhh0, bih1, bhh1, bias0, bias2);
  embed_kernel<<<16384, 256, 0, stream>>>(tokens, emb, xemb);

  for (int c = 0; c < 4; ++c) {
    proj_kernel<<<dim3(64, 32), 256, 0, stream>>>(xemb + (size_t)c * MCH * E_, wih0p, bias0, gates, E_);
    fused_kernel<<<192, 256, 0, stream>>>(whh0p, w2p, gates, bias2, h1, h2, c1buf, c2buf,
                                          c * TCH, TCH, flags);
  }
  // drain: L2 still owes t=511
  fused_kernel<<<192, 256, 0, stream>>>(whh0p, w2p, gates, bias2, h1, h2, c1buf, c2buf,
                                        512, 1, flags);
  head_kernel<<<1, 256, 0, stream>>>(h2 + (size_t)511 * BH, Wd, bd, out);

  (void)in_sizes; (void)n_in; (void)out_size; (void)ws_size;
}